// Round 6
// baseline (27.358 us; speedup 1.0000x reference)
//
#include <hip/hip_runtime.h>
#include <hip/hip_bf16.h>

#define HID 16
#define DIN 64
#define NK  32
#define NB  8192

typedef float v2f __attribute__((ext_vector_type(2)));
typedef float v4f __attribute__((ext_vector_type(4)));

// Hinge-form weights for one (k, d=lane): sum_h w2*relu(w1*x+b1)
//   = A*x + B + sum_h u_h*|x + c_h|   (exact: relu(a)=0.5*(a+|a|))
// The |.| is a free VOP3 input modifier -> 2 VALU ops per h instead of 3.
struct PW {
    float A, B;
    float u[HID];
    v2f   c[HID / 2];
};

__device__ __forceinline__ float pl_eval(const PW& w, float xd) {
    float a0 = fmaf(w.A, xd, w.B);
    float a1 = 0.f;
    const v2f xx = {xd, xd};
    #pragma unroll
    for (int hp = 0; hp < HID / 2; ++hp) {
        const v2f t = xx + w.c[hp];
        a0 = fmaf(fabsf(t.x), w.u[2 * hp],     a0);
        a1 = fmaf(fabsf(t.y), w.u[2 * hp + 1], a1);
    }
    return a0 + a1;
}

// lane = d. Hinge weights VGPR-resident (34 regs). LDS transpose per 16 rows.
// x loads for pass p+1 issued before pass p's compute retires (sw pipeline).
__global__ __launch_bounds__(256, 4) void kan_kernel(
    const float* __restrict__ x,
    const float* __restrict__ iw1, const float* __restrict__ ib1,
    const float* __restrict__ iw2, const float* __restrict__ ib2,
    const float* __restrict__ ow1, const float* __restrict__ ob1,
    const float* __restrict__ ow2, const float* __restrict__ ob2,
    float* __restrict__ out)
{
    __shared__ float lds[4][DIN * 17];

    const int t    = threadIdx.x;
    const int lane = t & 63;
    const int wid  = t >> 6;
    const int k    = blockIdx.x & (NK - 1);
    const int base = ((blockIdx.x >> 5) * 4 + wid) * 64;   // wave's 64 rows

    // ---- per-lane hinge-form precompute (once per wave) ----
    PW w;
    {
        v4f w1v[4], b1v[4], w2v[4];
        const v4f* p1 = (const v4f*)(iw1 + (k * DIN + lane) * HID);
        const v4f* p2 = (const v4f*)(ib1 + (k * DIN + lane) * HID);
        const v4f* p3 = (const v4f*)(iw2 + (k * DIN + lane) * HID);
        #pragma unroll
        for (int q = 0; q < 4; ++q) { w1v[q] = p1[q]; b1v[q] = p2[q]; w2v[q] = p3[q]; }

        float A = 0.f;
        float B = ib2[k * DIN + lane];   // fold inner L2 bias in here
        #pragma unroll
        for (int h = 0; h < HID; ++h) {
            const float w1 = w1v[h >> 2][h & 3];
            const float b1 = b1v[h >> 2][h & 3];
            const float w2 = w2v[h >> 2][h & 3];
            A = fmaf(0.5f * w2, w1, A);
            B = fmaf(0.5f * w2, b1, B);
            const float aw = fabsf(w1);
            const bool ok  = aw > 1e-20f;
            w.c[h >> 1][h & 1] = ok ? (b1 / w1) : 0.f;
            w.u[h]             = ok ? (0.5f * w2 * aw) : 0.f;
            if (!ok) B += 0.5f * w2 * fabsf(b1);
        }
        w.A = A; w.B = B;
    }

    float* __restrict__ myLds = lds[wid];
    const float* __restrict__ xp = x + base * DIN + lane;

    const int jj = lane & 15;   // row slot this lane reduces
    const int p  = lane >> 4;   // which 16 d's this lane sums

    float xr[16], xn[16], rsum[4];

    #pragma unroll
    for (int j = 0; j < 16; ++j) xr[j] = xp[j * DIN];

    #pragma unroll
    for (int pass = 0; pass < 4; ++pass) {
        if (pass < 3) {
            const float* __restrict__ xq = xp + (pass + 1) * 16 * DIN;
            #pragma unroll
            for (int j = 0; j < 16; ++j) xn[j] = xq[j * DIN];
        }
        #pragma unroll
        for (int j = 0; j < 16; ++j) {
            myLds[lane * 17 + j] = pl_eval(w, xr[j]);
        }
        float s = 0.f;
        #pragma unroll
        for (int i = 0; i < 16; ++i) {
            s += myLds[(p * 16 + i) * 17 + jj];
        }
        s += __shfl_xor(s, 16, 64);
        s += __shfl_xor(s, 32, 64);
        rsum[pass] = s;
        #pragma unroll
        for (int j = 0; j < 16; ++j) xr[j] = xn[j];
    }

    // Lane l owns row base+l: pass index = l>>4 (static select).
    const float sk = (lane & 32) ? ((lane & 16) ? rsum[3] : rsum[2])
                                 : ((lane & 16) ? rsum[1] : rsum[0]);

    // Outer net: scalar -> HID -> scalar (per k); ~2% of total work.
    float o = ob2[k];
    #pragma unroll
    for (int h = 0; h < HID; ++h) {
        const float g = fmaxf(fmaf(sk, ow1[k * HID + h], ob1[k * HID + h]), 0.f);
        o = fmaf(g, ow2[k * HID + h], o);
    }

    out[(base + lane) * NK + k] = o;
}

extern "C" void kernel_launch(void* const* d_in, const int* in_sizes, int n_in,
                              void* d_out, int out_size, void* d_ws, size_t ws_size,
                              hipStream_t stream) {
    const float* x   = (const float*)d_in[0];
    const float* iw1 = (const float*)d_in[1];
    const float* ib1 = (const float*)d_in[2];
    const float* iw2 = (const float*)d_in[3];
    const float* ib2 = (const float*)d_in[4];
    const float* ow1 = (const float*)d_in[5];
    const float* ob1 = (const float*)d_in[6];
    const float* ow2 = (const float*)d_in[7];
    const float* ob2 = (const float*)d_in[8];
    float* out = (float*)d_out;

    const int grid = (NB / 256) * NK;  // 1024 blocks, 4 waves each
    kan_kernel<<<grid, 256, 0, stream>>>(x, iw1, ib1, iw2, ib2,
                                         ow1, ob1, ow2, ob2, out);
}

// Round 7
// 27.076 us; speedup vs baseline: 1.0104x; 1.0104x over previous
//
#include <hip/hip_runtime.h>
#include <hip/hip_bf16.h>

#define HID 16
#define DIN 64
#define NK  32
#define NB  8192

typedef float v4f __attribute__((ext_vector_type(4)));

// Hinge form of one inner MLP (k, d=lane):
//   sum_h w2*relu(w1*x+b1) = A*x + B + sum_h u_h*|x + c_h|
// |.| is a free VOP3 modifier; each h = add + fma (both all-VGPR operands).
struct PW {
    float A, B;
    float u[HID];
    float c[HID];
};

__device__ __forceinline__ float pl_eval(const PW& w, float xd) {
    float a0 = fmaf(w.A, xd, w.B);
    float a1 = 0.f;
    #pragma unroll
    for (int h = 0; h < HID; h += 2) {
        const float t0 = xd + w.c[h];
        const float t1 = xd + w.c[h + 1];
        a0 = fmaf(fabsf(t0), w.u[h],     a0);
        a1 = fmaf(fabsf(t1), w.u[h + 1], a1);
    }
    return a0 + a1;
}

// lane = d, weights VGPR-resident. SAME algorithm as round 6, but the pass
// loop is a real loop (unroll disabled): hot code ~5 KB, I$-resident for all
// waves, instead of ~25 KB straight-line. x prefetch + reduce overlap inside
// the loop; per-lane cndmask select replaces the rsum[] array.
__global__ __launch_bounds__(256, 4) void kan_kernel(
    const float* __restrict__ x,
    const float* __restrict__ iw1, const float* __restrict__ ib1,
    const float* __restrict__ iw2, const float* __restrict__ ib2,
    const float* __restrict__ ow1, const float* __restrict__ ob1,
    const float* __restrict__ ow2, const float* __restrict__ ob2,
    float* __restrict__ out)
{
    __shared__ float lds[4][DIN * 17];

    const int t    = threadIdx.x;
    const int lane = t & 63;
    const int wid  = t >> 6;
    const int k    = blockIdx.x & (NK - 1);
    const int base = ((blockIdx.x >> 5) * 4 + wid) * 64;   // wave's 64 rows

    // ---- per-lane hinge precompute (once per wave; rcp instead of div) ----
    PW w;
    {
        v4f w1v[4], b1v[4], w2v[4];
        const v4f* p1 = (const v4f*)(iw1 + (k * DIN + lane) * HID);
        const v4f* p2 = (const v4f*)(ib1 + (k * DIN + lane) * HID);
        const v4f* p3 = (const v4f*)(iw2 + (k * DIN + lane) * HID);
        #pragma unroll
        for (int q = 0; q < 4; ++q) { w1v[q] = p1[q]; b1v[q] = p2[q]; w2v[q] = p3[q]; }

        float A = 0.f;
        float B = ib2[k * DIN + lane];   // fold inner L2 bias
        #pragma unroll
        for (int h = 0; h < HID; ++h) {
            const float w1  = w1v[h >> 2][h & 3];
            const float b1  = b1v[h >> 2][h & 3];
            const float w2h = w2v[h >> 2][h & 3];
            A = fmaf(0.5f * w2h, w1, A);
            B = fmaf(0.5f * w2h, b1, B);
            const float aw = fabsf(w1);
            const bool ok  = aw > 1e-20f;
            w.c[h] = ok ? b1 * __builtin_amdgcn_rcpf(w1) : 0.f;
            w.u[h] = ok ? 0.5f * w2h * aw : 0.f;
            if (!ok) B = fmaf(0.5f * w2h, fabsf(b1), B);
        }
        w.A = A; w.B = B;
    }

    float* __restrict__ myLds = lds[wid];
    const float* __restrict__ xp = x + base * DIN + lane;

    const int jj  = lane & 15;           // row slot this lane reduces
    const int pmy = lane >> 4;           // d-group this lane sums / its pass
    float* __restrict__ wb = myLds + lane * 17;              // write base
    const float* __restrict__ rb = myLds + (pmy * 16) * 17 + jj;  // read base

    // prologue: load pass-0 rows (static reg indices via unrolled loop)
    float xr[16];
    const float* __restrict__ xq = xp;
    #pragma unroll
    for (int j = 0; j < 16; ++j) xr[j] = xq[j * DIN];
    xq += 16 * DIN;

    float sk = 0.f;

    #pragma clang loop unroll(disable)
    for (int p = 0; p < 4; ++p) {
        // stage current pass into LDS (lane-major, pad 17 -> 2-way = free)
        #pragma unroll
        for (int j = 0; j < 16; ++j) wb[j] = pl_eval(w, xr[j]);
        // prefetch next pass's x while reduce runs
        if (p < 3) {
            #pragma unroll
            for (int j = 0; j < 16; ++j) xr[j] = xq[j * DIN];
            xq += 16 * DIN;
        }
        // transpose-reduce current pass
        float s = 0.f;
        #pragma unroll
        for (int i = 0; i < 16; ++i) s += rb[i * 17];
        s += __shfl_xor(s, 16, 64);
        s += __shfl_xor(s, 32, 64);
        sk = (p == pmy) ? s : sk;        // lane keeps only its own pass
    }

    // Outer net: scalar -> HID -> scalar (per k); ~2% of work.
    float o = ob2[k];
    #pragma unroll
    for (int h = 0; h < HID; ++h) {
        const float g = fmaxf(fmaf(sk, ow1[k * HID + h], ob1[k * HID + h]), 0.f);
        o = fmaf(g, ow2[k * HID + h], o);
    }

    out[(base + lane) * NK + k] = o;
}

extern "C" void kernel_launch(void* const* d_in, const int* in_sizes, int n_in,
                              void* d_out, int out_size, void* d_ws, size_t ws_size,
                              hipStream_t stream) {
    const float* x   = (const float*)d_in[0];
    const float* iw1 = (const float*)d_in[1];
    const float* ib1 = (const float*)d_in[2];
    const float* iw2 = (const float*)d_in[3];
    const float* ib2 = (const float*)d_in[4];
    const float* ow1 = (const float*)d_in[5];
    const float* ob1 = (const float*)d_in[6];
    const float* ow2 = (const float*)d_in[7];
    const float* ob2 = (const float*)d_in[8];
    float* out = (float*)d_out;

    const int grid = (NB / 256) * NK;  // 1024 blocks, 4 waves each
    kan_kernel<<<grid, 256, 0, stream>>>(x, iw1, ib1, iw2, ib2,
                                         ow1, ob1, ow2, ob2, out);
}